// Round 24
// baseline (272.670 us; speedup 1.0000x reference)
//
#include <hip/hip_runtime.h>
#include <hip/hip_bf16.h>

typedef __bf16 bf16;
typedef __bf16 bf16x4 __attribute__((ext_vector_type(4)));
typedef __bf16 bf16x8 __attribute__((ext_vector_type(8)));
typedef float f32x4 __attribute__((ext_vector_type(4)));
typedef float f32x16 __attribute__((ext_vector_type(16)));
typedef unsigned u32x4 __attribute__((ext_vector_type(4)));

#define MFMA16(a, b, c) __builtin_amdgcn_mfma_f32_16x16x32_bf16((a), (b), (c), 0, 0, 0)
#define MFMA32(a, b, c) __builtin_amdgcn_mfma_f32_32x32x16_bf16((a), (b), (c), 0, 0, 0)

// XCD-chunked block swizzle (nblk % 8 == 0): each XCD gets a contiguous chunk.
__device__ __forceinline__ int xcd_swizzle(int bid, int nblk) {
  const int per = nblk >> 3;
  return (bid & 7) * per + (bid >> 3);
}

__device__ __forceinline__ void gload_lds16(const bf16* g, bf16* lds) {
  __builtin_amdgcn_global_load_lds(
      (const __attribute__((address_space(1))) void*)g,
      (__attribute__((address_space(3))) void*)lds, 16, 0, 0);
}

// Raw hardware exp2 (1 trans instr). Verified correct r18-r23.
__device__ __forceinline__ float fast_exp2(float x) {
  float r;
  asm("v_exp_f32 %0, %1\n\ts_nop 1" : "=v"(r) : "v"(x));
  return r;
}

// Packed f32x2 -> bf16x2 convert (1 instr, RNE). Verified correct r18-r23.
__device__ __forceinline__ unsigned cvt_pk_bf16(float lo, float hi) {
  unsigned r;
  asm("v_cvt_pk_bf16_f32 %0, %1, %2" : "=v"(r) : "v"(lo), "v"(hi));
  return r;
}

// ---------------- GEMM machinery (128x128 tile, BK=32, 1-barrier) ----------
// fp32 fallback path (r23, proven): reg-stage + cvt_pk.
template <typename T> struct StageRegs;
template <> struct StageRegs<float> { float4 lo[2], hi[2]; };
template <> struct StageRegs<bf16> { bf16x8 v[2]; };

template <typename T>
__device__ __forceinline__ void stage_issue(StageRegs<T>& r, const T* base,
                                            int brc, int k0, int tid) {
#pragma unroll
  for (int i = 0; i < 2; ++i) {
    const int c = i * 256 + tid;     // 512 chunks of 8 elems = 128x32
    const int row = c >> 2, lin = c & 3;
    const T* p = base + (size_t)(brc + row) * 1024 + k0 + lin * 8;
    if constexpr (sizeof(T) == 4) {
      r.lo[i] = *reinterpret_cast<const float4*>(p);
      r.hi[i] = *reinterpret_cast<const float4*>(p + 4);
    } else {
      r.v[i] = *reinterpret_cast<const bf16x8*>(p);
    }
  }
}

template <typename T>
__device__ __forceinline__ void stage_write(const StageRegs<T>& r, bf16* sm,
                                            int tid) {
#pragma unroll
  for (int i = 0; i < 2; ++i) {
    const int c = i * 256 + tid;
    const int row = c >> 2, lin = c & 3;
    const int slot = lin ^ (row & 3);
    if constexpr (sizeof(T) == 4) {
      const float4 a = r.lo[i], b = r.hi[i];
      u32x4 w;
      w[0] = cvt_pk_bf16(a.x, a.y);
      w[1] = cvt_pk_bf16(a.z, a.w);
      w[2] = cvt_pk_bf16(b.x, b.y);
      w[3] = cvt_pk_bf16(b.z, b.w);
      *reinterpret_cast<u32x4*>(sm + row * 32 + slot * 8) = w;
    } else {
      *reinterpret_cast<bf16x8*>(sm + row * 32 + slot * 8) = r.v[i];
    }
  }
}

template <typename TA>
__device__ __forceinline__ void gemm_core(const TA* A, const float* W,
                                          int brow, int bcol, int tid, int wm,
                                          int wn, int l15, int l4,
                                          bf16 (*Asm)[4096], bf16 (*Bsm)[4096],
                                          f32x4 (&acc)[4][4]) {
  StageRegs<TA> ra;
  StageRegs<float> rb;
  stage_issue(ra, A, brow, 0, tid);
  stage_issue(rb, W, bcol, 0, tid);
  int p = 0;
  for (int t = 0; t < 32; ++t) {
    stage_write(ra, Asm[p], tid);   // compiler waits vmcnt for ra/rb here
    stage_write(rb, Bsm[p], tid);
    __syncthreads();                // publish buffer p
    if (t + 1 < 32) {
      stage_issue(ra, A, brow, (t + 1) << 5, tid);  // fly under compute
      stage_issue(rb, W, bcol, (t + 1) << 5, tid);
    }
    bf16x8 af[4], bfr[4];
#pragma unroll
    for (int m = 0; m < 4; ++m) {
      const int row = wm + m * 16 + l15;
      const int slot = l4 ^ (row & 3);
      af[m] = *reinterpret_cast<const bf16x8*>(Asm[p] + row * 32 + slot * 8);
    }
#pragma unroll
    for (int n = 0; n < 4; ++n) {
      const int row = wn + n * 16 + l15;
      const int slot = l4 ^ (row & 3);
      bfr[n] = *reinterpret_cast<const bf16x8*>(Bsm[p] + row * 32 + slot * 8);
    }
    __builtin_amdgcn_s_setprio(1);
#pragma unroll
    for (int m = 0; m < 4; ++m)
#pragma unroll
      for (int n = 0; n < 4; ++n)
        acc[m][n] = MFMA16(af[m], bfr[n], acc[m][n]);
    __builtin_amdgcn_s_setprio(0);
    p ^= 1;
  }
}

// Shared qkv epilogue: seg 0 -> Qws (x qscale), seg 1 -> Kws, seg 2 -> Vt^T.
__device__ __forceinline__ void qkv_epilogue(
    int seg, const float* bias, f32x4 (&acc)[4][4], int r0, int c0,
    bf16* Qws, bf16* Kws, bf16* Vt, float qscale) {
  if (seg < 2) {
    bf16* C = seg == 0 ? Qws : Kws;
    const float cs = seg == 0 ? qscale : 1.0f;
#pragma unroll
    for (int n = 0; n < 4; ++n) {
      const float bvv = bias[c0 + n * 16];
#pragma unroll
      for (int m = 0; m < 4; ++m)
#pragma unroll
        for (int r = 0; r < 4; ++r)
          C[(size_t)(r0 + m * 16 + r) * 1024 + (c0 + n * 16)] =
              (bf16)((acc[m][n][r] + bvv) * cs);
    }
  } else {
#pragma unroll
    for (int n = 0; n < 4; ++n) {
      const float bvv = bias[c0 + n * 16];
      const int col = c0 + n * 16;
#pragma unroll
      for (int m = 0; m < 4; ++m) {
        const int row = r0 + m * 16;
        const int bq_ = row >> 11;
        const int srow = row & 2047;
        uint2 w;
        w.x = cvt_pk_bf16(acc[m][n][0] + bvv, acc[m][n][1] + bvv);
        w.y = cvt_pk_bf16(acc[m][n][2] + bvv, acc[m][n][3] + bvv);
        *reinterpret_cast<uint2*>(
            &Vt[(size_t)(bq_ * 1024 + col) * 2048 + srow]) = w;
      }
    }
  }
}

// fp32-input qkv (fallback, r23 proven).
__global__ __launch_bounds__(256, 2) void qkv_gemm_kernel(
    const float* __restrict__ query, const float* __restrict__ key,
    const float* __restrict__ value, const float* __restrict__ wq,
    const float* __restrict__ wk, const float* __restrict__ wv,
    const float* __restrict__ bq, const float* __restrict__ bk,
    const float* __restrict__ bv, bf16* __restrict__ Qws,
    bf16* __restrict__ Kws, bf16* __restrict__ Vt, float qscale) {
  __shared__ bf16 Asm[2][128 * 32];
  __shared__ bf16 Bsm[2][128 * 32];
  const int tid = threadIdx.x;
  const int lane = tid & 63;
  const int wid = tid >> 6;
  const int l15 = lane & 15;
  const int l4 = lane >> 4;
  const int bid = xcd_swizzle(blockIdx.x, 1536);
  const int seg = bid / 512;
  const int inner = bid % 512;
  const int brow = (inner >> 3) << 7;
  const int bcol = (inner & 7) << 7;
  const int wm = (wid >> 1) << 6;
  const int wn = (wid & 1) << 6;

  const float* A = seg == 0 ? query : (seg == 1 ? key : value);
  const float* W = seg == 0 ? wq : (seg == 1 ? wk : wv);
  const float* bias = seg == 0 ? bq : (seg == 1 ? bk : bv);

  f32x4 acc[4][4] = {};
  gemm_core(A, W, brow, bcol, tid, wm, wn, l15, l4, Asm, Bsm, acc);
  qkv_epilogue(seg, bias, acc, brow + wm + l4 * 4, bcol + wn + l15, Qws, Kws,
               Vt, qscale);
}

// bf16-input qkv (fast path): both operands pre-converted; staging via
// global_load_lds with pre-swizzled SOURCE (linear dest; attn's proven
// pattern) -> ZERO staging VALU on the critical path. One counted
// vmcnt(0)+barrier per tile (only stage(t) is in flight at the wait).
__global__ __launch_bounds__(256, 2) void qkv_gemm_bf16_kernel(
    const bf16* __restrict__ qbf, const bf16* __restrict__ kbf,
    const bf16* __restrict__ vbf, const bf16* __restrict__ wqb,
    const bf16* __restrict__ wkb, const bf16* __restrict__ wvb,
    const float* __restrict__ bq, const float* __restrict__ bk,
    const float* __restrict__ bv, bf16* __restrict__ Qws,
    bf16* __restrict__ Kws, bf16* __restrict__ Vt, float qscale) {
  __shared__ bf16 Asm[2][128 * 32];
  __shared__ bf16 Bsm[2][128 * 32];
  const int tid = threadIdx.x;
  const int lane = tid & 63;
  const int wid = tid >> 6;
  const int l15 = lane & 15;
  const int l4 = lane >> 4;
  const int bid = xcd_swizzle(blockIdx.x, 1536);
  const int seg = bid / 512;
  const int inner = bid % 512;
  const int brow = (inner >> 3) << 7;
  const int bcol = (inner & 7) << 7;
  const int wm = (wid >> 1) << 6;
  const int wn = (wid & 1) << 6;

  const bf16* A = seg == 0 ? qbf : (seg == 1 ? kbf : vbf);
  const bf16* W = seg == 0 ? wqb : (seg == 1 ? wkb : wvb);
  const float* bias = seg == 0 ? bq : (seg == 1 ? bk : bv);

  // Staging pointers: chunk c -> row=c>>2, lin=c&3; source col pre-swizzled
  // so LDS[row*32+s*8] = A[row][(s^(row&3))*8] (matches the read side).
  const int c0_ = tid, c1_ = 256 + tid;
  const int r0s = c0_ >> 2, s0s = ((c0_ & 3) ^ (r0s & 3)) * 8;
  const int r1s = c1_ >> 2, s1s = ((c1_ & 3) ^ (r1s & 3)) * 8;
  const bf16* ga0 = A + (size_t)(brow + r0s) * 1024 + s0s;
  const bf16* ga1 = A + (size_t)(brow + r1s) * 1024 + s1s;
  const bf16* gb0 = W + (size_t)(bcol + r0s) * 1024 + s0s;
  const bf16* gb1 = W + (size_t)(bcol + r1s) * 1024 + s1s;

  f32x4 acc[4][4] = {};
  int p = 0;
  // prologue: stage tile 0 into buf0
  gload_lds16(ga0, &Asm[0][tid * 8]);
  gload_lds16(ga1, &Asm[0][2048 + tid * 8]);
  gload_lds16(gb0, &Bsm[0][tid * 8]);
  gload_lds16(gb1, &Bsm[0][2048 + tid * 8]);
  ga0 += 32; ga1 += 32; gb0 += 32; gb1 += 32;

  for (int t = 0; t < 32; ++t) {
    asm volatile("s_waitcnt vmcnt(0)" ::: "memory");  // stage(t) landed
    __builtin_amdgcn_s_barrier();                     // publish buf p
    __builtin_amdgcn_sched_barrier(0);
    if (t + 1 < 32) {  // stage(t+1) -> other buffer, flies under compute(t)
      gload_lds16(ga0, &Asm[p ^ 1][tid * 8]);
      gload_lds16(ga1, &Asm[p ^ 1][2048 + tid * 8]);
      gload_lds16(gb0, &Bsm[p ^ 1][tid * 8]);
      gload_lds16(gb1, &Bsm[p ^ 1][2048 + tid * 8]);
      ga0 += 32; ga1 += 32; gb0 += 32; gb1 += 32;
    }
    bf16x8 af[4], bfr[4];
#pragma unroll
    for (int m = 0; m < 4; ++m) {
      const int row = wm + m * 16 + l15;
      const int slot = l4 ^ (row & 3);
      af[m] = *reinterpret_cast<const bf16x8*>(Asm[p] + row * 32 + slot * 8);
    }
#pragma unroll
    for (int n = 0; n < 4; ++n) {
      const int row = wn + n * 16 + l15;
      const int slot = l4 ^ (row & 3);
      bfr[n] = *reinterpret_cast<const bf16x8*>(Bsm[p] + row * 32 + slot * 8);
    }
    __builtin_amdgcn_s_setprio(1);
#pragma unroll
    for (int m = 0; m < 4; ++m)
#pragma unroll
      for (int n = 0; n < 4; ++n)
        acc[m][n] = MFMA16(af[m], bfr[n], acc[m][n]);
    __builtin_amdgcn_s_setprio(0);
    p ^= 1;
  }
  qkv_epilogue(seg, bias, acc, brow + wm + l4 * 4, bcol + wn + l15, Qws, Kws,
               Vt, qscale);
}

// Output projection GEMM (bf16 ctx @ fp32 wo^T + bo -> fp32 out).
__global__ __launch_bounds__(256, 2) void out_gemm_kernel(
    const bf16* __restrict__ A, const float* __restrict__ W,
    const float* __restrict__ bias, float* __restrict__ C) {
  __shared__ bf16 Asm[2][128 * 32];
  __shared__ bf16 Bsm[2][128 * 32];
  const int tid = threadIdx.x;
  const int lane = tid & 63;
  const int wid = tid >> 6;
  const int l15 = lane & 15;
  const int l4 = lane >> 4;
  const int bid = xcd_swizzle(blockIdx.x, 512);
  const int brow = (bid >> 3) << 7;
  const int bcol = (bid & 7) << 7;
  const int wm = (wid >> 1) << 6;
  const int wn = (wid & 1) << 6;

  f32x4 acc[4][4] = {};
  gemm_core(A, W, brow, bcol, tid, wm, wn, l15, l4, Asm, Bsm, acc);

  const int r0 = brow + wm + l4 * 4;
  const int c0 = bcol + wn + l15;
#pragma unroll
  for (int n = 0; n < 4; ++n) {
    const float bvv = bias[c0 + n * 16];
#pragma unroll
    for (int m = 0; m < 4; ++m)
#pragma unroll
      for (int r = 0; r < 4; ++r)
        C[(size_t)(r0 + m * 16 + r) * 1024 + (c0 + n * 16)] =
            acc[m][n][r] + bvv;
  }
}

// Prep: tiled bf16 mask (*log2e) + (optional) linear fp32->bf16 conversion of
// Q/K/V inputs and wq/wk/wv (RNE cvt_pk == the in-GEMM conversion it
// replaces, so results are bit-identical). No LDS -> full occupancy.
__global__ __launch_bounds__(256) void prep_kernel(
    const float* __restrict__ mask, bf16* __restrict__ M2,
    const float* __restrict__ query, const float* __restrict__ key,
    const float* __restrict__ value, const float* __restrict__ wq,
    const float* __restrict__ wk, const float* __restrict__ wv,
    bf16* __restrict__ qbf, bf16* __restrict__ kbf, bf16* __restrict__ vbf,
    bf16* __restrict__ wqb, bf16* __restrict__ wkb, bf16* __restrict__ wvb,
    int do_conv) {
  const float LOG2E = 1.44269504088896f;
  const int T0 = blockIdx.x * 256 + threadIdx.x;  // < 524288
#pragma unroll
  for (int i = 0; i < 4; ++i) {
    const int O = T0 + i * 524288;
    const int a = O & 3;
    const int h5 = (O >> 2) & 1;
    const int q = (O >> 3) & 2047;
    const int t = (O >> 14) & 31;
    const int b = O >> 19;
    const float* src = mask + ((size_t)(b * 2048 + q)) * 2048 + t * 64 +
                       32 * (a >> 1) + 16 * (a & 1) + 8 * h5;
    const float4 x = *reinterpret_cast<const float4*>(src);
    const float4 y = *reinterpret_cast<const float4*>(src + 4);
    u32x4 w;
    w[0] = cvt_pk_bf16(x.x * LOG2E, x.y * LOG2E);
    w[1] = cvt_pk_bf16(x.z * LOG2E, x.w * LOG2E);
    w[2] = cvt_pk_bf16(y.x * LOG2E, y.y * LOG2E);
    w[3] = cvt_pk_bf16(y.z * LOG2E, y.w * LOG2E);
    *reinterpret_cast<u32x4*>(&M2[(size_t)O * 8]) = w;
  }
  if (do_conv) {
    // inputs: 3 x 1048576 units of 8 elems; exactly 6 full strides.
#pragma unroll
    for (int i = 0; i < 6; ++i) {
      const int u = T0 + i * 524288;
      const int seg = u >> 20;
      const size_t off = (size_t)(u & 1048575) * 8;
      const float* s = (seg == 0 ? query : (seg == 1 ? key : value)) + off;
      bf16* d = (seg == 0 ? qbf : (seg == 1 ? kbf : vbf)) + off;
      const float4 x = *reinterpret_cast<const float4*>(s);
      const float4 y = *reinterpret_cast<const float4*>(s + 4);
      u32x4 w;
      w[0] = cvt_pk_bf16(x.x, x.y);
      w[1] = cvt_pk_bf16(x.z, x.w);
      w[2] = cvt_pk_bf16(y.x, y.y);
      w[3] = cvt_pk_bf16(y.z, y.w);
      *reinterpret_cast<u32x4*>(d) = w;
    }
    // weights: 3 x 131072 units, single partial stride.
    if (T0 < 393216) {
      const int seg = T0 >> 17;
      const size_t off = (size_t)(T0 & 131071) * 8;
      const float* s = (seg == 0 ? wq : (seg == 1 ? wk : wv)) + off;
      bf16* d = (seg == 0 ? wqb : (seg == 1 ? wkb : wvb)) + off;
      const float4 x = *reinterpret_cast<const float4*>(s);
      const float4 y = *reinterpret_cast<const float4*>(s + 4);
      u32x4 w;
      w[0] = cvt_pk_bf16(x.x, x.y);
      w[1] = cvt_pk_bf16(x.z, x.w);
      w[2] = cvt_pk_bf16(y.x, y.y);
      w[3] = cvt_pk_bf16(y.z, y.w);
      *reinterpret_cast<u32x4*>(d) = w;
    }
  }
}

// ---------------- Flash attention: r21/r23 kernel (best measured) ----------
__global__ __launch_bounds__(256, 3) void attn_kernel(
    const bf16* __restrict__ Q, const bf16* __restrict__ Kt,
    const bf16* __restrict__ Vt, const bf16* __restrict__ M2,
    bf16* __restrict__ ctx) {
  __shared__ bf16 Ksm[2][64 * 64];
  __shared__ bf16 Vsm[2][64 * 64];
  const int lid = xcd_swizzle(blockIdx.x, 1024);
  const int h = lid & 15;
  const int qb = (lid >> 4) & 15;
  const int b = lid >> 8;
  const int tid = threadIdx.x;
  const int lane = tid & 63;
  const int wid = tid >> 6;
  const int l31 = lane & 31;
  const int h5 = lane >> 5;
  const int qbase = qb * 128 + wid * 32;

  bf16x8 qf[4];
#pragma unroll
  for (int c = 0; c < 4; ++c)
    qf[c] = *reinterpret_cast<const bf16x8*>(
        &Q[(size_t)(b * 2048 + qbase + l31) * 1024 + h * 64 + c * 16 + h5 * 8]);

  f32x16 o[2] = {};
  float lrow = 0.f;

  const bf16* Kb = Kt + (size_t)b * 2048 * 1024 + h * 64;
  const bf16* Vb = Vt + (size_t)(b * 16 + h) * 64 * 2048;

  const int ca = tid, cb = 256 + tid;
  const int ra_ = ca >> 3, la = (ca & 7) ^ (ra_ & 7);
  const int rb_ = cb >> 3, lb = (cb & 7) ^ (rb_ & 7);
  const int pra = (ra_ & 51) | ((ra_ & 4) << 1) | ((ra_ & 8) >> 1);
  const int prb = (rb_ & 51) | ((rb_ & 4) << 1) | ((rb_ & 8) >> 1);
  const bf16* kga = Kb + (size_t)pra * 1024 + la * 8;
  const bf16* kgb = Kb + (size_t)prb * 1024 + lb * 8;
  const bf16* vga = Vb + (size_t)ra_ * 2048 + la * 8;
  const bf16* vgb = Vb + (size_t)rb_ * 2048 + lb * 8;
  const bf16* mp =
      M2 + ((size_t)(b * 32) * 2048 + qbase + l31) * 64 + h5 * 32;

  auto stage = [&](int p) {
    gload_lds16(kga, &Ksm[p][tid * 8]);
    gload_lds16(kgb, &Ksm[p][2048 + tid * 8]);
    gload_lds16(vga, &Vsm[p][tid * 8]);
    gload_lds16(vgb, &Vsm[p][2048 + tid * 8]);
    kga += 64 * 1024; kgb += 64 * 1024;
    vga += 64; vgb += 64;
  };
  u32x4 mA[4], mB[4];
  auto load_mask = [&](u32x4(&mr)[4]) {
#pragma unroll
    for (int i = 0; i < 4; ++i)
      mr[i] = *reinterpret_cast<const u32x4*>(mp + i * 8);
    mp += 2048 * 64;
  };

  auto tile_compute = [&](int p, u32x4(&mr)[4]) {
    f32x16 sf[2];
#pragma unroll
    for (int w = 0; w < 16; ++w) {
      const unsigned word = mr[w >> 2][w & 3];
      const int s = w >> 3;
      const int base = ((w >> 1) & 3) * 4 + (w & 1) * 2;
      sf[s][base + 0] = __builtin_bit_cast(float, word << 16);
      sf[s][base + 1] = __builtin_bit_cast(float, word & 0xffff0000u);
    }

    __builtin_amdgcn_s_setprio(1);
#pragma unroll
    for (int s = 0; s < 2; ++s) {
#pragma unroll
      for (int c = 0; c < 4; ++c) {
        const int row = s * 32 + l31;
        const int slot = (2 * c + h5) ^ (row & 7);
        const bf16x8 kf =
            *reinterpret_cast<const bf16x8*>(&Ksm[p][row * 64 + slot * 8]);
        sf[s] = MFMA32(kf, qf[c], sf[s]);
      }
    }
    __builtin_amdgcn_s_setprio(0);

    unsigned pk[2][4][2];
#pragma unroll
    for (int s = 0; s < 2; ++s) {
#pragma unroll
      for (int g = 0; g < 4; ++g) {
        const float p0 = fast_exp2(sf[s][g * 4 + 0]);
        const float p1 = fast_exp2(sf[s][g * 4 + 1]);
        const float p2 = fast_exp2(sf[s][g * 4 + 2]);
        const float p3 = fast_exp2(sf[s][g * 4 + 3]);
        lrow += (p0 + p1) + (p2 + p3);
        pk[s][g][0] = cvt_pk_bf16(p0, p1);
        pk[s][g][1] = cvt_pk_bf16(p2, p3);
      }
    }

    __builtin_amdgcn_s_setprio(1);
#pragma unroll
    for (int c = 0; c < 4; ++c) {
      const int s = c >> 1;
      const int g0 = 2 * (c & 1);
      const u32x4 uu = {pk[s][g0][0], pk[s][g0][1], pk[s][g0 + 1][0],
                        pk[s][g0 + 1][1]};
      const bf16x8 pa = __builtin_bit_cast(bf16x8, uu);
#pragma unroll
      for (int dsub = 0; dsub < 2; ++dsub) {
        const int row = dsub * 32 + l31;
        const int slot = (2 * c + h5) ^ (row & 7);
        const bf16x8 vf =
            *reinterpret_cast<const bf16x8*>(&Vsm[p][row * 64 + slot * 8]);
        o[dsub] = MFMA32(pa, vf, o[dsub]);
      }
    }
    __builtin_amdgcn_s_setprio(0);
  };

  stage(0);
  load_mask(mA);

  for (int t = 0; t < 32; t += 2) {
    if (t + 1 < 32) {
      stage(1);
      load_mask(mB);
      asm volatile("s_waitcnt vmcnt(8)" ::: "memory");
    } else {
      asm volatile("s_waitcnt vmcnt(0)" ::: "memory");
    }
    __builtin_amdgcn_s_barrier();
    __builtin_amdgcn_sched_barrier(0);
    tile_compute(0, mA);
    __builtin_amdgcn_s_barrier();
    if (t + 2 < 32) {
      stage(0);
      load_mask(mA);
      asm volatile("s_waitcnt vmcnt(8)" ::: "memory");
    } else {
      asm volatile("s_waitcnt vmcnt(0)" ::: "memory");
    }
    __builtin_amdgcn_s_barrier();
    __builtin_amdgcn_sched_barrier(0);
    tile_compute(1, mB);
    __builtin_amdgcn_s_barrier();
  }

  lrow += __shfl_xor(lrow, 32, 64);
  const float linv = __builtin_amdgcn_rcpf(lrow);
#pragma unroll
  for (int reg = 0; reg < 16; ++reg) {
    const int qr = (reg & 3) + 8 * (reg >> 2) + 4 * h5;
    const float li = __shfl(linv, qr, 64);
    const int q = qbase + qr;
#pragma unroll
    for (int dsub = 0; dsub < 2; ++dsub) {
      ctx[(size_t)(b * 2048 + q) * 1024 + h * 64 + dsub * 32 + l31] =
          (bf16)(o[dsub][reg] * li);
    }
  }
}

extern "C" void kernel_launch(void* const* d_in, const int* in_sizes, int n_in,
                              void* d_out, int out_size, void* d_ws,
                              size_t ws_size, hipStream_t stream) {
  const float* key = (const float*)d_in[0];
  const float* query = (const float*)d_in[1];
  const float* value = (const float*)d_in[2];
  const float* mask = (const float*)d_in[3];
  const float* wq = (const float*)d_in[4];
  const float* bq = (const float*)d_in[5];
  const float* wk = (const float*)d_in[6];
  const float* bk = (const float*)d_in[7];
  const float* wv = (const float*)d_in[8];
  const float* bv = (const float*)d_in[9];
  const float* wo = (const float*)d_in[10];
  const float* bo = (const float*)d_in[11];
  float* out = (float*)d_out;

  const size_t NBSH = (size_t)4 * 2048 * 1024;   // 8,388,608 elems
  bf16* Qws = (bf16*)d_ws;     // Q (pre-scaled), later ctx in place
  bf16* Kws = Qws + NBSH;
  bf16* Vt = Kws + NBSH;       // base ws: 50.33 MB
  bf16* qbf = Qws + 3 * NBSH;  // optional bf16 inputs/weights (+56.6 MB)
  bf16* kbf = Qws + 4 * NBSH;
  bf16* vbf = Qws + 5 * NBSH;
  bf16* wqb = Qws + 6 * NBSH;
  bf16* wkb = wqb + 1048576;
  bf16* wvb = wkb + 1048576;
  bf16* M2 = (bf16*)d_out;     // tiled bf16 mask*log2e in d_out

  // 6*NBSH*2 + 3*1024*1024*2 = 106,954,752 bytes needed for the fast path.
  const bool conv = ws_size >= (size_t)106954752;

  prep_kernel<<<2048, dim3(256), 0, stream>>>(
      mask, M2, query, key, value, wq, wk, wv, qbf, kbf, vbf, wqb, wkb, wvb,
      conv ? 1 : 0);
  if (conv) {
    qkv_gemm_bf16_kernel<<<1536, dim3(256), 0, stream>>>(
        qbf, kbf, vbf, wqb, wkb, wvb, bq, bk, bv, Qws, Kws, Vt,
        0.18033688011112f);
  } else {
    qkv_gemm_kernel<<<1536, dim3(256), 0, stream>>>(
        query, key, value, wq, wk, wv, bq, bk, bv, Qws, Kws, Vt,
        0.18033688011112f);
  }
  attn_kernel<<<1024, dim3(256), 0, stream>>>(Qws, Kws, Vt, M2, Qws);
  out_gemm_kernel<<<512, dim3(256), 0, stream>>>(Qws, wo, bo, out);
}

// Round 25
// 259.761 us; speedup vs baseline: 1.0497x; 1.0497x over previous
//
#include <hip/hip_runtime.h>
#include <hip/hip_bf16.h>

typedef __bf16 bf16;
typedef __bf16 bf16x4 __attribute__((ext_vector_type(4)));
typedef __bf16 bf16x8 __attribute__((ext_vector_type(8)));
typedef float f32x4 __attribute__((ext_vector_type(4)));
typedef float f32x16 __attribute__((ext_vector_type(16)));
typedef unsigned u32x4 __attribute__((ext_vector_type(4)));

#define MFMA16(a, b, c) __builtin_amdgcn_mfma_f32_16x16x32_bf16((a), (b), (c), 0, 0, 0)
#define MFMA32(a, b, c) __builtin_amdgcn_mfma_f32_32x32x16_bf16((a), (b), (c), 0, 0, 0)

// XCD-chunked block swizzle (nblk % 8 == 0): each XCD gets a contiguous chunk.
__device__ __forceinline__ int xcd_swizzle(int bid, int nblk) {
  const int per = nblk >> 3;
  return (bid & 7) * per + (bid >> 3);
}

__device__ __forceinline__ void gload_lds16(const bf16* g, bf16* lds) {
  __builtin_amdgcn_global_load_lds(
      (const __attribute__((address_space(1))) void*)g,
      (__attribute__((address_space(3))) void*)lds, 16, 0, 0);
}

// Raw hardware exp2 (1 trans instr). Verified correct r18-r24.
__device__ __forceinline__ float fast_exp2(float x) {
  float r;
  asm("v_exp_f32 %0, %1\n\ts_nop 1" : "=v"(r) : "v"(x));
  return r;
}

// Packed f32x2 -> bf16x2 convert (1 instr, RNE). Verified correct r18-r24.
__device__ __forceinline__ unsigned cvt_pk_bf16(float lo, float hi) {
  unsigned r;
  asm("v_cvt_pk_bf16_f32 %0, %1, %2" : "=v"(r) : "v"(lo), "v"(hi));
  return r;
}

// ---------------- GEMM machinery (128x128 tile, BK=32, 1-barrier) ----------
template <typename T> struct StageRegs;
template <> struct StageRegs<float> { float4 lo[2], hi[2]; };
template <> struct StageRegs<bf16> { bf16x8 v[2]; };

template <typename T>
__device__ __forceinline__ void stage_issue(StageRegs<T>& r, const T* base,
                                            int brc, int k0, int tid) {
#pragma unroll
  for (int i = 0; i < 2; ++i) {
    const int c = i * 256 + tid;     // 512 chunks of 8 elems = 128x32
    const int row = c >> 2, lin = c & 3;
    const T* p = base + (size_t)(brc + row) * 1024 + k0 + lin * 8;
    if constexpr (sizeof(T) == 4) {
      r.lo[i] = *reinterpret_cast<const float4*>(p);
      r.hi[i] = *reinterpret_cast<const float4*>(p + 4);
    } else {
      r.v[i] = *reinterpret_cast<const bf16x8*>(p);
    }
  }
}

template <typename T>
__device__ __forceinline__ void stage_write(const StageRegs<T>& r, bf16* sm,
                                            int tid) {
#pragma unroll
  for (int i = 0; i < 2; ++i) {
    const int c = i * 256 + tid;
    const int row = c >> 2, lin = c & 3;
    const int slot = lin ^ (row & 3);
    if constexpr (sizeof(T) == 4) {
      const float4 a = r.lo[i], b = r.hi[i];
      u32x4 w;
      w[0] = cvt_pk_bf16(a.x, a.y);
      w[1] = cvt_pk_bf16(a.z, a.w);
      w[2] = cvt_pk_bf16(b.x, b.y);
      w[3] = cvt_pk_bf16(b.z, b.w);
      *reinterpret_cast<u32x4*>(sm + row * 32 + slot * 8) = w;
    } else {
      *reinterpret_cast<bf16x8*>(sm + row * 32 + slot * 8) = r.v[i];
    }
  }
}

// Main loop: 32 K-tiles of 32; ONE barrier/tile; stage_issue(t+1) after the
// barrier so loads fly under compute(t). Race-safe (r20-r23 verified form).
template <typename TA>
__device__ __forceinline__ void gemm_core(const TA* A, const float* W,
                                          int brow, int bcol, int tid, int wm,
                                          int wn, int l15, int l4,
                                          bf16 (*Asm)[4096], bf16 (*Bsm)[4096],
                                          f32x4 (&acc)[4][4]) {
  StageRegs<TA> ra;
  StageRegs<float> rb;
  stage_issue(ra, A, brow, 0, tid);
  stage_issue(rb, W, bcol, 0, tid);
  int p = 0;
  for (int t = 0; t < 32; ++t) {
    stage_write(ra, Asm[p], tid);   // compiler waits vmcnt for ra/rb here
    stage_write(rb, Bsm[p], tid);
    __syncthreads();                // publish buffer p
    if (t + 1 < 32) {
      stage_issue(ra, A, brow, (t + 1) << 5, tid);  // fly under compute
      stage_issue(rb, W, bcol, (t + 1) << 5, tid);
    }
    bf16x8 af[4], bfr[4];
#pragma unroll
    for (int m = 0; m < 4; ++m) {
      const int row = wm + m * 16 + l15;
      const int slot = l4 ^ (row & 3);
      af[m] = *reinterpret_cast<const bf16x8*>(Asm[p] + row * 32 + slot * 8);
    }
#pragma unroll
    for (int n = 0; n < 4; ++n) {
      const int row = wn + n * 16 + l15;
      const int slot = l4 ^ (row & 3);
      bfr[n] = *reinterpret_cast<const bf16x8*>(Bsm[p] + row * 32 + slot * 8);
    }
    __builtin_amdgcn_s_setprio(1);
#pragma unroll
    for (int m = 0; m < 4; ++m)
#pragma unroll
      for (int n = 0; n < 4; ++n)
        acc[m][n] = MFMA16(af[m], bfr[n], acc[m][n]);
    __builtin_amdgcn_s_setprio(0);
    p ^= 1;
  }
}

// Fused QKV projection. seg 0 -> Qws (x log2e/8), seg 1 -> Kws,
// seg 2 -> Vt written TRANSPOSED.
__global__ __launch_bounds__(256, 2) void qkv_gemm_kernel(
    const float* __restrict__ query, const float* __restrict__ key,
    const float* __restrict__ value, const float* __restrict__ wq,
    const float* __restrict__ wk, const float* __restrict__ wv,
    const float* __restrict__ bq, const float* __restrict__ bk,
    const float* __restrict__ bv, bf16* __restrict__ Qws,
    bf16* __restrict__ Kws, bf16* __restrict__ Vt, float qscale) {
  __shared__ bf16 Asm[2][128 * 32];
  __shared__ bf16 Bsm[2][128 * 32];
  const int tid = threadIdx.x;
  const int lane = tid & 63;
  const int wid = tid >> 6;
  const int l15 = lane & 15;
  const int l4 = lane >> 4;
  const int bid = xcd_swizzle(blockIdx.x, 1536);
  const int seg = bid / 512;
  const int inner = bid % 512;
  const int brow = (inner >> 3) << 7;
  const int bcol = (inner & 7) << 7;
  const int wm = (wid >> 1) << 6;
  const int wn = (wid & 1) << 6;

  const float* A = seg == 0 ? query : (seg == 1 ? key : value);
  const float* W = seg == 0 ? wq : (seg == 1 ? wk : wv);
  const float* bias = seg == 0 ? bq : (seg == 1 ? bk : bv);

  f32x4 acc[4][4] = {};
  gemm_core(A, W, brow, bcol, tid, wm, wn, l15, l4, Asm, Bsm, acc);

  const int r0 = brow + wm + l4 * 4;
  const int c0 = bcol + wn + l15;
  if (seg < 2) {
    bf16* C = seg == 0 ? Qws : Kws;
    const float cs = seg == 0 ? qscale : 1.0f;
#pragma unroll
    for (int n = 0; n < 4; ++n) {
      const float bvv = bias[c0 + n * 16];
#pragma unroll
      for (int m = 0; m < 4; ++m)
#pragma unroll
        for (int r = 0; r < 4; ++r)
          C[(size_t)(r0 + m * 16 + r) * 1024 + (c0 + n * 16)] =
              (bf16)((acc[m][n][r] + bvv) * cs);
    }
  } else {
    // Vt[b*1024 + col][s] = V[row][col]; rows r=0..3 are s-consecutive.
#pragma unroll
    for (int n = 0; n < 4; ++n) {
      const float bvv = bias[c0 + n * 16];
      const int col = c0 + n * 16;
#pragma unroll
      for (int m = 0; m < 4; ++m) {
        const int row = r0 + m * 16;
        const int bq_ = row >> 11;
        const int srow = row & 2047;
        uint2 w;
        w.x = cvt_pk_bf16(acc[m][n][0] + bvv, acc[m][n][1] + bvv);
        w.y = cvt_pk_bf16(acc[m][n][2] + bvv, acc[m][n][3] + bvv);
        *reinterpret_cast<uint2*>(
            &Vt[(size_t)(bq_ * 1024 + col) * 2048 + srow]) = w;
      }
    }
  }
}

// Output projection GEMM (bf16 ctx @ fp32 wo^T + bo -> fp32 out).
__global__ __launch_bounds__(256, 2) void out_gemm_kernel(
    const bf16* __restrict__ A, const float* __restrict__ W,
    const float* __restrict__ bias, float* __restrict__ C) {
  __shared__ bf16 Asm[2][128 * 32];
  __shared__ bf16 Bsm[2][128 * 32];
  const int tid = threadIdx.x;
  const int lane = tid & 63;
  const int wid = tid >> 6;
  const int l15 = lane & 15;
  const int l4 = lane >> 4;
  const int bid = xcd_swizzle(blockIdx.x, 512);
  const int brow = (bid >> 3) << 7;
  const int bcol = (bid & 7) << 7;
  const int wm = (wid >> 1) << 6;
  const int wn = (wid & 1) << 6;

  f32x4 acc[4][4] = {};
  gemm_core(A, W, brow, bcol, tid, wm, wn, l15, l4, Asm, Bsm, acc);

  const int r0 = brow + wm + l4 * 4;
  const int c0 = bcol + wn + l15;
#pragma unroll
  for (int n = 0; n < 4; ++n) {
    const float bvv = bias[c0 + n * 16];
#pragma unroll
    for (int m = 0; m < 4; ++m)
#pragma unroll
      for (int r = 0; r < 4; ++r)
        C[(size_t)(r0 + m * 16 + r) * 1024 + (c0 + n * 16)] =
            acc[m][n][r] + bvv;
  }
}

// Standalone tiled-mask prep (no LDS -> full occupancy).
// M2[((b*32+t)*2048+q)*64 + h5*32 + s*16 + g*4 + r]
//   = bf16( mask[b][q][t*64 + 32s + 16(g>>1) + 4(g&1) + 8h5 + r] * log2e )
__global__ __launch_bounds__(256) void prep_mask_kernel(
    const float* __restrict__ mask, bf16* __restrict__ M2) {
  const float LOG2E = 1.44269504088896f;
  const int T0 = blockIdx.x * 256 + threadIdx.x;
#pragma unroll
  for (int i = 0; i < 4; ++i) {
    const int O = T0 + i * 524288;
    const int a = O & 3;
    const int h5 = (O >> 2) & 1;
    const int q = (O >> 3) & 2047;
    const int t = (O >> 14) & 31;
    const int b = O >> 19;
    const float* src = mask + ((size_t)(b * 2048 + q)) * 2048 + t * 64 +
                       32 * (a >> 1) + 16 * (a & 1) + 8 * h5;
    const float4 x = *reinterpret_cast<const float4*>(src);
    const float4 y = *reinterpret_cast<const float4*>(src + 4);
    u32x4 w;
    w[0] = cvt_pk_bf16(x.x * LOG2E, x.y * LOG2E);
    w[1] = cvt_pk_bf16(x.z * LOG2E, x.w * LOG2E);
    w[2] = cvt_pk_bf16(y.x * LOG2E, y.y * LOG2E);
    w[3] = cvt_pk_bf16(y.z * LOG2E, y.w * LOG2E);
    *reinterpret_cast<u32x4*>(&M2[(size_t)O * 8]) = w;
  }
}

// ---------------- Flash attention: r21/r23 kernel (best measured) ----------
// Block = (b, h, 128 q); 4 waves x 32 q; 2 LDS buffers (32 KB); (256,3)
// bounds (caps <=128 VGPR spill: r7/r13/r18). Counted vmcnt(8) + raw-barrier
// loop; tiled bf16 mask; pi-permuted K keeps P lane-local for PV; raw
// v_exp_f32 + v_cvt_pk_bf16_f32; Q pre-scaled by log2e/8; fixed-shift
// softmax (exact).
__global__ __launch_bounds__(256, 3) void attn_kernel(
    const bf16* __restrict__ Q, const bf16* __restrict__ Kt,
    const bf16* __restrict__ Vt, const bf16* __restrict__ M2,
    bf16* __restrict__ ctx) {
  __shared__ bf16 Ksm[2][64 * 64];
  __shared__ bf16 Vsm[2][64 * 64];
  const int lid = xcd_swizzle(blockIdx.x, 1024);
  const int h = lid & 15;
  const int qb = (lid >> 4) & 15;
  const int b = lid >> 8;
  const int tid = threadIdx.x;
  const int lane = tid & 63;
  const int wid = tid >> 6;
  const int l31 = lane & 31;
  const int h5 = lane >> 5;
  const int qbase = qb * 128 + wid * 32;

  bf16x8 qf[4];
#pragma unroll
  for (int c = 0; c < 4; ++c)
    qf[c] = *reinterpret_cast<const bf16x8*>(
        &Q[(size_t)(b * 2048 + qbase + l31) * 1024 + h * 64 + c * 16 + h5 * 8]);

  f32x16 o[2] = {};
  float lrow = 0.f;

  const bf16* Kb = Kt + (size_t)b * 2048 * 1024 + h * 64;
  const bf16* Vb = Vt + (size_t)(b * 16 + h) * 64 * 2048;

  const int ca = tid, cb = 256 + tid;
  const int ra_ = ca >> 3, la = (ca & 7) ^ (ra_ & 7);
  const int rb_ = cb >> 3, lb = (cb & 7) ^ (rb_ & 7);
  const int pra = (ra_ & 51) | ((ra_ & 4) << 1) | ((ra_ & 8) >> 1);
  const int prb = (rb_ & 51) | ((rb_ & 4) << 1) | ((rb_ & 8) >> 1);
  const bf16* kga = Kb + (size_t)pra * 1024 + la * 8;
  const bf16* kgb = Kb + (size_t)prb * 1024 + lb * 8;
  const bf16* vga = Vb + (size_t)ra_ * 2048 + la * 8;
  const bf16* vgb = Vb + (size_t)rb_ * 2048 + lb * 8;
  const bf16* mp =
      M2 + ((size_t)(b * 32) * 2048 + qbase + l31) * 64 + h5 * 32;

  auto stage = [&](int p) {
    gload_lds16(kga, &Ksm[p][tid * 8]);
    gload_lds16(kgb, &Ksm[p][2048 + tid * 8]);
    gload_lds16(vga, &Vsm[p][tid * 8]);
    gload_lds16(vgb, &Vsm[p][2048 + tid * 8]);
    kga += 64 * 1024; kgb += 64 * 1024;
    vga += 64; vgb += 64;
  };
  u32x4 mA[4], mB[4];
  auto load_mask = [&](u32x4(&mr)[4]) {
#pragma unroll
    for (int i = 0; i < 4; ++i)
      mr[i] = *reinterpret_cast<const u32x4*>(mp + i * 8);
    mp += 2048 * 64;
  };

  auto tile_compute = [&](int p, u32x4(&mr)[4]) {
    f32x16 sf[2];
#pragma unroll
    for (int w = 0; w < 16; ++w) {
      const unsigned word = mr[w >> 2][w & 3];
      const int s = w >> 3;
      const int base = ((w >> 1) & 3) * 4 + (w & 1) * 2;
      sf[s][base + 0] = __builtin_bit_cast(float, word << 16);
      sf[s][base + 1] = __builtin_bit_cast(float, word & 0xffff0000u);
    }

    __builtin_amdgcn_s_setprio(1);
#pragma unroll
    for (int s = 0; s < 2; ++s) {
#pragma unroll
      for (int c = 0; c < 4; ++c) {
        const int row = s * 32 + l31;
        const int slot = (2 * c + h5) ^ (row & 7);
        const bf16x8 kf =
            *reinterpret_cast<const bf16x8*>(&Ksm[p][row * 64 + slot * 8]);
        sf[s] = MFMA32(kf, qf[c], sf[s]);
      }
    }
    __builtin_amdgcn_s_setprio(0);

    unsigned pk[2][4][2];
#pragma unroll
    for (int s = 0; s < 2; ++s) {
#pragma unroll
      for (int g = 0; g < 4; ++g) {
        const float p0 = fast_exp2(sf[s][g * 4 + 0]);
        const float p1 = fast_exp2(sf[s][g * 4 + 1]);
        const float p2 = fast_exp2(sf[s][g * 4 + 2]);
        const float p3 = fast_exp2(sf[s][g * 4 + 3]);
        lrow += (p0 + p1) + (p2 + p3);
        pk[s][g][0] = cvt_pk_bf16(p0, p1);
        pk[s][g][1] = cvt_pk_bf16(p2, p3);
      }
    }

    __builtin_amdgcn_s_setprio(1);
#pragma unroll
    for (int c = 0; c < 4; ++c) {
      const int s = c >> 1;
      const int g0 = 2 * (c & 1);
      const u32x4 uu = {pk[s][g0][0], pk[s][g0][1], pk[s][g0 + 1][0],
                        pk[s][g0 + 1][1]};
      const bf16x8 pa = __builtin_bit_cast(bf16x8, uu);
#pragma unroll
      for (int dsub = 0; dsub < 2; ++dsub) {
        const int row = dsub * 32 + l31;
        const int slot = (2 * c + h5) ^ (row & 7);
        const bf16x8 vf =
            *reinterpret_cast<const bf16x8*>(&Vsm[p][row * 64 + slot * 8]);
        o[dsub] = MFMA32(pa, vf, o[dsub]);
      }
    }
    __builtin_amdgcn_s_setprio(0);
  };

  stage(0);
  load_mask(mA);

  for (int t = 0; t < 32; t += 2) {
    if (t + 1 < 32) {
      stage(1);
      load_mask(mB);
      asm volatile("s_waitcnt vmcnt(8)" ::: "memory");
    } else {
      asm volatile("s_waitcnt vmcnt(0)" ::: "memory");
    }
    __builtin_amdgcn_s_barrier();
    __builtin_amdgcn_sched_barrier(0);
    tile_compute(0, mA);
    __builtin_amdgcn_s_barrier();
    if (t + 2 < 32) {
      stage(0);
      load_mask(mA);
      asm volatile("s_waitcnt vmcnt(8)" ::: "memory");
    } else {
      asm volatile("s_waitcnt vmcnt(0)" ::: "memory");
    }
    __builtin_amdgcn_s_barrier();
    __builtin_amdgcn_sched_barrier(0);
    tile_compute(1, mB);
    __builtin_amdgcn_s_barrier();
  }

  lrow += __shfl_xor(lrow, 32, 64);
  const float linv = __builtin_amdgcn_rcpf(lrow);
#pragma unroll
  for (int reg = 0; reg < 16; ++reg) {
    const int qr = (reg & 3) + 8 * (reg >> 2) + 4 * h5;
    const float li = __shfl(linv, qr, 64);
    const int q = qbase + qr;
#pragma unroll
    for (int dsub = 0; dsub < 2; ++dsub) {
      ctx[(size_t)(b * 2048 + q) * 1024 + h * 64 + dsub * 32 + l31] =
          (bf16)(o[dsub][reg] * li);
    }
  }
}

extern "C" void kernel_launch(void* const* d_in, const int* in_sizes, int n_in,
                              void* d_out, int out_size, void* d_ws,
                              size_t ws_size, hipStream_t stream) {
  const float* key = (const float*)d_in[0];
  const float* query = (const float*)d_in[1];
  const float* value = (const float*)d_in[2];
  const float* mask = (const float*)d_in[3];
  const float* wq = (const float*)d_in[4];
  const float* bq = (const float*)d_in[5];
  const float* wk = (const float*)d_in[6];
  const float* bk = (const float*)d_in[7];
  const float* wv = (const float*)d_in[8];
  const float* bv = (const float*)d_in[9];
  const float* wo = (const float*)d_in[10];
  const float* bo = (const float*)d_in[11];
  float* out = (float*)d_out;

  const size_t NBSH = (size_t)4 * 2048 * 1024;
  bf16* Qws = (bf16*)d_ws;     // Q (pre-scaled by log2e/8), later ctx in place
  bf16* Kws = Qws + NBSH;
  bf16* Vt = Kws + NBSH;       // total ws use: 50.3 MB
  bf16* M2 = (bf16*)d_out;     // tiled bf16 mask*log2e in d_out (33.5 MB,
                               // dead until out_gemm overwrites it)

  prep_mask_kernel<<<2048, dim3(256), 0, stream>>>(mask, M2);
  qkv_gemm_kernel<<<1536, dim3(256), 0, stream>>>(query, key, value, wq, wk,
                                                  wv, bq, bk, bv, Qws, Kws, Vt,
                                                  0.18033688011112f);
  attn_kernel<<<1024, dim3(256), 0, stream>>>(Qws, Kws, Vt, M2, Qws);
  out_gemm_kernel<<<512, dim3(256), 0, stream>>>(Qws, wo, bo, out);
}